// Round 9
// baseline (571.726 us; speedup 1.0000x reference)
//
#include <hip/hip_runtime.h>
#include <math.h>

#define NN 10000
#define EE 100000
#define EPE 110000   // edges + self loops
#define CC 200
#define MPAD 10112   // 158 * 64

typedef __attribute__((ext_vector_type(8))) _Float16 f16x8;
typedef __attribute__((ext_vector_type(4))) _Float16 f16x4;
typedef __attribute__((ext_vector_type(4))) unsigned short u16x4;
typedef __attribute__((ext_vector_type(4))) float f32x4;

__device__ __forceinline__ float lrelu(float v) { return v >= 0.f ? v : 0.2f * v; }
__device__ __forceinline__ float gelu_f(float v) { return 0.5f * v * (1.f + erff(v * 0.70710678118654752f)); }

// ---------------- CSR build ----------------

__global__ void build_edges_kernel(const int* __restrict__ ei,
                                   int* __restrict__ src_all, int* __restrict__ dst_all,
                                   int* __restrict__ deg) {
    int e = blockIdx.x * blockDim.x + threadIdx.x;
    if (e >= EPE) return;
    int s, d;
    if (e < EE) { s = ei[e]; d = ei[EE + e]; }
    else        { s = e - EE; d = e - EE; }
    src_all[e] = s;
    dst_all[e] = d;
    atomicAdd(&deg[d], 1);
}

__global__ void scan_kernel(const int* __restrict__ deg, int* __restrict__ row_ptr, int n) {
    __shared__ int wsum[16];
    int tid = threadIdx.x;
    int lane = tid & 63, w = tid >> 6;
    int carry = 0;
    for (int base = 0; base < n; base += 1024) {
        int idx = base + tid;
        int v = (idx < n) ? deg[idx] : 0;
        int x = v;
#pragma unroll
        for (int off = 1; off < 64; off <<= 1) {
            int t = __shfl_up(x, off);
            if (lane >= off) x += t;
        }
        if (lane == 63) wsum[w] = x;
        __syncthreads();
        if (w == 0) {
            int s = (lane < 16) ? wsum[lane] : 0;
#pragma unroll
            for (int off = 1; off < 16; off <<= 1) {
                int t = __shfl_up(s, off);
                if (lane >= off) s += t;
            }
            if (lane < 16) wsum[lane] = s;
        }
        __syncthreads();
        int woff = (w > 0) ? wsum[w - 1] : 0;
        if (idx < n) row_ptr[idx] = carry + woff + x - v;   // exclusive
        carry += wsum[15];
        __syncthreads();
    }
    if (tid == 0) row_ptr[n] = carry;
}

__global__ void scatter_kernel(const int* __restrict__ src_all, const int* __restrict__ dst_all,
                               const int* __restrict__ row_ptr, int* __restrict__ cursor,
                               int* __restrict__ col_src, int* __restrict__ col_eid) {
    int e = blockIdx.x * blockDim.x + threadIdx.x;
    if (e >= EPE) return;
    int d = dst_all[e];
    int pos = row_ptr[d] + atomicAdd(&cursor[d], 1);
    col_src[pos] = src_all[e];
    col_eid[pos] = e;
}

// ---------------- fp16 conversion ----------------

__global__ void convA_kernel(const float* __restrict__ x, int sx, int Fin, int Kp,
                             unsigned short* __restrict__ Ap) {
    size_t idx = (size_t)blockIdx.x * 256 + threadIdx.x;
    if (idx >= (size_t)MPAD * Kp) return;
    int row = (int)(idx / Kp);
    int kk  = (int)(idx % Kp);
    float v = 0.f;
    if (row < NN && kk < Fin) v = x[(size_t)row * sx + kk];
    Ap[idx] = __builtin_bit_cast(unsigned short, (_Float16)v);
}

// zero only the pad regions of Ap [MPAD][832] (agg writes rows<NN, cols<800)
__global__ void padA_kernel(unsigned short* __restrict__ Ap) {
    int idx = blockIdx.x * 256 + threadIdx.x;
    if (idx < NN * 32) {
        int rw = idx >> 5, c = idx & 31;
        Ap[(size_t)rw * 832 + 800 + c] = 0;
    } else {
        int j = idx - NN * 32;
        if (j < (MPAD - NN) * 832) {
            int rw = j / 832, c = j - rw * 832;
            Ap[(size_t)(NN + rw) * 832 + c] = 0;
        }
    }
}

// all 5 layers' B' (transposed [n][k]) in one dispatch; slot stride 896*832
__global__ void convB_all_kernel(const float* __restrict__ W0, const float* __restrict__ W1,
                                 const float* __restrict__ W2, const float* __restrict__ W3,
                                 const float* __restrict__ W4,
                                 unsigned short* __restrict__ Bp) {
    int l = blockIdx.y;
    const float* W = (l == 0) ? W0 : (l == 1) ? W1 : (l == 2) ? W2 : (l == 3) ? W3 : W4;
    int Fin = (l == 0) ? 200 : 800;
    int HC  = (l == 4) ? 200 : 800;
    int Kp  = (l == 0) ? 256 : 832;
    int Np  = (l == 4) ? 256 : 896;
    int idx = blockIdx.x * 256 + threadIdx.x;
    if (idx >= Np * Kp) return;
    int n = idx / Kp, kk = idx - n * Kp;
    float v = 0.f;
    if (n < HC && kk < Fin) v = W[(size_t)kk * HC + n];
    Bp[(size_t)l * (896 * 832) + idx] = __builtin_bit_cast(unsigned short, (_Float16)v);
}

// ---------------- MFMA GEMM + attention-score partials ----------------
// 64x128 tile, BK=64, 4 waves, 16x16x32 f16 MFMA, global_load_lds w16,
// XOR chunk swizzle via pre-swizzled source, XCD-bijective block swizzle.
// 3-buffer LDS pipeline, 2-tiles-ahead staging, counted vmcnt(12),
// hoisted LDS read offsets (no per-iteration address VALU).

__global__ __launch_bounds__(256) void gemm_mfma(const unsigned short* __restrict__ A,
                                                 const unsigned short* __restrict__ B,
                                                 unsigned short* __restrict__ C,
                                                 const float* __restrict__ a_s,
                                                 const float* __restrict__ a_d,
                                                 float* __restrict__ g_as,
                                                 float* __restrict__ g_ad,
                                                 int Kt, int Np, int ncol, int HC, int H) {
    __shared__ unsigned short As[3][4096];   // 3 x 8 KB  (64 rows x 64 k)
    __shared__ unsigned short Bs[3][8192];   // 3 x 16 KB (128 rows x 64 k)

    int tid = threadIdx.x;
    int lane = tid & 63, wave = tid >> 6;

    int nwg = gridDim.x;
    int orig = blockIdx.x;
    int q = nwg >> 3, r = nwg & 7;
    int xcd = orig & 7, sidx = orig >> 3;
    int wg = (xcd < r ? xcd * (q + 1) : r * (q + 1) + (xcd - r) * q) + sidx;
    int rowT = wg / ncol, colT = wg - rowT * ncol;
    int row0 = rowT * 64, col0 = colT * 128;
    int wr = wave >> 1, wc = wave & 1;

    size_t gAoff[2], gBoff[4];
    int ldsSegA[2], ldsSegB[4];
#pragma unroll
    for (int i = 0; i < 2; ++i) {
        int seg = wave * 2 + i;
        int chunkIdx = seg * 64 + lane;
        int rr = chunkIdx >> 3;
        int c = chunkIdx & 7;
        int cg = c ^ (rr & 7);
        gAoff[i] = (size_t)(row0 + rr) * Kt + (size_t)cg * 8;
        ldsSegA[i] = seg * 512;
    }
#pragma unroll
    for (int i = 0; i < 4; ++i) {
        int seg = wave * 4 + i;
        int chunkIdx = seg * 64 + lane;
        int rr = chunkIdx >> 3;
        int c = chunkIdx & 7;
        int cg = c ^ (rr & 7);
        gBoff[i] = (size_t)(col0 + rr) * Kt + (size_t)cg * 8;
        ldsSegB[i] = seg * 512;
    }

    int rowA[2], rowB[4];
#pragma unroll
    for (int m = 0; m < 2; ++m) rowA[m] = wr * 32 + m * 16 + (lane & 15);
#pragma unroll
    for (int n = 0; n < 4; ++n) rowB[n] = wc * 64 + n * 16 + (lane & 15);

    // hoisted LDS read offsets (per kh, static after unroll)
    int iaOff[2][2], ibOff[2][4];
#pragma unroll
    for (int kh = 0; kh < 2; ++kh) {
        int cw = kh * 4 + (lane >> 4);
#pragma unroll
        for (int m = 0; m < 2; ++m)
            iaOff[kh][m] = rowA[m] * 64 + ((cw ^ (rowA[m] & 7)) << 3);
#pragma unroll
        for (int n = 0; n < 4; ++n)
            ibOff[kh][n] = rowB[n] * 64 + ((cw ^ (rowB[n] & 7)) << 3);
    }

    f32x4 acc[2][4];
#pragma unroll
    for (int m = 0; m < 2; ++m)
#pragma unroll
        for (int n = 0; n < 4; ++n) acc[m][n] = f32x4{0.f, 0.f, 0.f, 0.f};

#define STAGE(bufi, kk)                                                                     \
    _Pragma("unroll")                                                                       \
    for (int i = 0; i < 2; ++i)                                                             \
        __builtin_amdgcn_global_load_lds(                                                   \
            (const __attribute__((address_space(1))) void*)(A + gAoff[i] + (kk)),           \
            (__attribute__((address_space(3))) void*)(&As[bufi][ldsSegA[i]]), 16, 0, 0);    \
    _Pragma("unroll")                                                                       \
    for (int i = 0; i < 4; ++i)                                                             \
        __builtin_amdgcn_global_load_lds(                                                   \
            (const __attribute__((address_space(1))) void*)(B + gBoff[i] + (kk)),           \
            (__attribute__((address_space(3))) void*)(&Bs[bufi][ldsSegB[i]]), 16, 0, 0);

    int nk = Kt >> 6;
    STAGE(0, 0)
    if (nk > 1) STAGE(1, 64)

    int cur = 0;
    for (int t = 0; t < nk; ++t) {
        if (t + 2 < nk) {
            int b2 = cur + 2; if (b2 >= 3) b2 -= 3;
            STAGE(b2, (t + 2) * 64)
        }
        int rem = nk - 1 - t;
        if (rem >= 2)      { asm volatile("s_waitcnt vmcnt(12)" ::: "memory"); }
        else if (rem == 1) { asm volatile("s_waitcnt vmcnt(6)"  ::: "memory"); }
        else               { asm volatile("s_waitcnt vmcnt(0)"  ::: "memory"); }
        __builtin_amdgcn_s_barrier();
        __builtin_amdgcn_sched_barrier(0);

        const unsigned short* asb = As[cur];
        const unsigned short* bsb = Bs[cur];
#pragma unroll
        for (int kh = 0; kh < 2; ++kh) {
            f16x8 a[2], b[4];
#pragma unroll
            for (int m = 0; m < 2; ++m) a[m] = *(const f16x8*)(&asb[iaOff[kh][m]]);
#pragma unroll
            for (int n = 0; n < 4; ++n) b[n] = *(const f16x8*)(&bsb[ibOff[kh][n]]);
            if (kh == 0) __builtin_amdgcn_s_setprio(1);
#pragma unroll
            for (int m = 0; m < 2; ++m)
#pragma unroll
                for (int n = 0; n < 4; ++n)
                    acc[m][n] = __builtin_amdgcn_mfma_f32_16x16x32_f16(a[m], b[n], acc[m][n], 0, 0, 0);
        }
        __builtin_amdgcn_s_setprio(0);
        asm volatile("s_waitcnt lgkmcnt(0)" ::: "memory");
        __builtin_amdgcn_sched_barrier(0);
        __builtin_amdgcn_s_barrier();
        __builtin_amdgcn_sched_barrier(0);
        cur = (cur + 1 == 3) ? 0 : cur + 1;
    }
#undef STAGE

    int crow = row0 + wr * 32 + ((lane >> 4) << 2);
    int ccol = col0 + wc * 64 + (lane & 15);
#pragma unroll
    for (int m = 0; m < 2; ++m)
#pragma unroll
        for (int j = 0; j < 4; ++j) {
            size_t rb = (size_t)(crow + m * 16 + j) * Np;
#pragma unroll
            for (int n = 0; n < 4; ++n)
                C[rb + ccol + n * 16] =
                    __builtin_bit_cast(unsigned short, (_Float16)acc[m][n][j]);
        }

    // ---- attention-score partials (no atomics) ----
    int base = col0 + wc * 64;      // wave-uniform 64-col window
    int hA = base / CC;
    float sAs[2][8], sAd[2][8];
#pragma unroll
    for (int b = 0; b < 2; ++b)
#pragma unroll
        for (int k = 0; k < 8; ++k) { sAs[b][k] = 0.f; sAd[b][k] = 0.f; }
#pragma unroll
    for (int n = 0; n < 4; ++n) {
        int c = ccol + n * 16;
        if (c < HC) {
            int hd = c / CC;
            int cm = c - hd * CC;
            float asv = a_s[hd * CC + cm];
            float adv = a_d[hd * CC + cm];
            int b = hd - hA;
#pragma unroll
            for (int m = 0; m < 2; ++m)
#pragma unroll
                for (int j = 0; j < 4; ++j) {
                    sAs[b][m * 4 + j] += acc[m][n][j] * asv;
                    sAd[b][m * 4 + j] += acc[m][n][j] * adv;
                }
        }
    }
#pragma unroll
    for (int off = 1; off < 16; off <<= 1) {
#pragma unroll
        for (int b = 0; b < 2; ++b)
#pragma unroll
            for (int k = 0; k < 8; ++k) {
                sAs[b][k] += __shfl_xor(sAs[b][k], off);
                sAd[b][k] += __shfl_xor(sAd[b][k], off);
            }
    }
    if ((lane & 15) == 0) {
        int slice = colT * 2 + wc;
        float* pas = g_as + (size_t)slice * NN * H;
        float* pad2 = g_ad + (size_t)slice * NN * H;
#pragma unroll
        for (int b = 0; b < 2; ++b) {
            int hd = hA + b;
            if (hd >= H) continue;
#pragma unroll
            for (int m = 0; m < 2; ++m)
#pragma unroll
                for (int j = 0; j < 4; ++j) {
                    int row = crow + m * 16 + j;
                    if (row < NN) {
                        pas[row * H + hd] = sAs[b][m * 4 + j];
                        pad2[row * H + hd] = sAd[b][m * 4 + j];
                    }
                }
        }
    }
}

// fold per-window partials into final asrc/adst (static window<->head overlap)
__global__ void fold_attn_kernel(const float* __restrict__ g_as, const float* __restrict__ g_ad,
                                 float* __restrict__ asrc, float* __restrict__ adst, int H) {
    int i = blockIdx.x * 256 + threadIdx.x;
    if (i >= NN * H) return;
    int hd = i % H;
    int w0 = (CC * hd) >> 6, w1 = (CC * hd + CC - 1) >> 6;
    float sa = 0.f, sd = 0.f;
    for (int w = w0; w <= w1; ++w) {
        sa += g_as[(size_t)w * NN * H + i];
        sd += g_ad[(size_t)w * NN * H + i];
    }
    asrc[i] = sa;
    adst[i] = sd;
}

// ---------------- fused softmax(m/den) + weights + aggregation + bias + gelu ----------------

__global__ __launch_bounds__(256) void fused_agg_kernel(const unsigned short* __restrict__ h,
                                                        const float* __restrict__ asrc,
                                                        const float* __restrict__ adst,
                                                        const int* __restrict__ row_ptr,
                                                        const int* __restrict__ col_src,
                                                        const int* __restrict__ col_eid,
                                                        const float* __restrict__ bias,
                                                        float* __restrict__ out32,
                                                        unsigned short* __restrict__ apn,
                                                        float* __restrict__ wout,
                                                        int H, int HC, int HCp) {
    int n = blockIdx.x;
    int tid = threadIdx.x;
    int wave = tid >> 6, lane = tid & 63;
    int beg = row_ptr[n], end = row_ptr[n + 1];

    __shared__ float m_s[4], inv_s[4], ad_s[4];
    __shared__ float w_lds[64 * 4];
    __shared__ int src_lds[64];

    if (wave < H) {
        float ad = adst[n * H + wave];
        float m = -1e30f, den = 0.f;
        for (int e = beg + lane; e < end; e += 64) {
            float v = lrelu(asrc[col_src[e] * H + wave] + ad);
            if (v > m) { den = den * expf(m - v) + 1.f; m = v; }
            else den += expf(v - m);
        }
#pragma unroll
        for (int off = 1; off < 64; off <<= 1) {
            float m2 = __shfl_xor(m, off);
            float d2 = __shfl_xor(den, off);
            float M = fmaxf(m, m2);
            den = den * expf(m - M) + d2 * expf(m2 - M);
            m = M;
        }
        if (lane == 0) { m_s[wave] = m; inv_s[wave] = 1.f / den; ad_s[wave] = ad; }
    }
    __syncthreads();

    int ch0 = tid * 4;
    int head = ch0 / CC;
    float a0 = 0.f, a1 = 0.f, a2 = 0.f, a3 = 0.f;

    for (int c0 = beg; c0 < end; c0 += 64) {
        int cnt = min(64, end - c0);
        if (wave < H && lane < cnt) {
            int e = c0 + lane;
            int s = col_src[e];
            float v = lrelu(asrc[s * H + wave] + ad_s[wave]);
            float wv = expf(v - m_s[wave]) * inv_s[wave];
            w_lds[lane * 4 + wave] = wv;
            if (wave == 0) src_lds[lane] = s;
            if (wout) wout[(size_t)col_eid[e] * H + wave] = wv;
        }
        __syncthreads();
        if (ch0 < HC) {
            // 2-deep prefetch pipeline
            f16x4 hva = {}, hvb = {};
            hva = *(const f16x4*)(h + (size_t)src_lds[0] * HCp + ch0);
            if (cnt > 1) hvb = *(const f16x4*)(h + (size_t)src_lds[1] * HCp + ch0);
            for (int j = 0; j < cnt; ++j) {
                f16x4 hvc = {};
                if (j + 2 < cnt) hvc = *(const f16x4*)(h + (size_t)src_lds[j + 2] * HCp + ch0);
                float wv = w_lds[j * 4 + head];
                a0 += wv * (float)hva[0];
                a1 += wv * (float)hva[1];
                a2 += wv * (float)hva[2];
                a3 += wv * (float)hva[3];
                hva = hvb; hvb = hvc;
            }
        }
        __syncthreads();
    }

    if (ch0 < HC) {
        float4 bv = *(const float4*)(bias + ch0);
        float g0 = gelu_f(a0 + bv.x), g1 = gelu_f(a1 + bv.y);
        float g2 = gelu_f(a2 + bv.z), g3 = gelu_f(a3 + bv.w);
        if (out32) {
            *(float4*)(out32 + (size_t)n * HC + ch0) = float4{g0, g1, g2, g3};
        } else {
            *(u16x4*)(apn + (size_t)n * 832 + ch0) = u16x4{
                __builtin_bit_cast(unsigned short, (_Float16)g0),
                __builtin_bit_cast(unsigned short, (_Float16)g1),
                __builtin_bit_cast(unsigned short, (_Float16)g2),
                __builtin_bit_cast(unsigned short, (_Float16)g3)};
        }
    }
}

// ---------------- host ----------------

extern "C" void kernel_launch(void* const* d_in, const int* in_sizes, int n_in,
                              void* d_out, int out_size, void* d_ws, size_t ws_size,
                              hipStream_t stream) {
    const float* X = (const float*)d_in[0];
    const int* ei = (const int*)d_in[1];

    char* ws = (char*)d_ws;
    size_t off = 0;
    auto alloc = [&](size_t bytes) { void* p = ws + off; off += (bytes + 255) & ~(size_t)255; return p; };

    unsigned short* Ap0 = (unsigned short*)alloc((size_t)MPAD * 256 * 2);       // 5.2 MB
    unsigned short* Ap  = (unsigned short*)alloc((size_t)MPAD * 832 * 2);       // 16.8 MB
    unsigned short* Bp  = (unsigned short*)alloc((size_t)5 * 896 * 832 * 2);    // 7.5 MB
    unsigned short* hbuf= (unsigned short*)alloc((size_t)MPAD * 896 * 2);       // 18.1 MB
    float* g_as  = (float*)alloc((size_t)14 * NN * 4 * 4);                      // 2.24 MB
    float* g_ad  = (float*)alloc((size_t)14 * NN * 4 * 4);                      // 2.24 MB
    float* attn_all = (float*)alloc((size_t)5 * 2 * NN * 4 * 4);                // 1.6 MB
    int* src_all  = (int*)alloc((size_t)EPE * 4);
    int* dst_all  = (int*)alloc((size_t)EPE * 4);
    int* col_src  = (int*)alloc((size_t)EPE * 4);
    int* col_eid  = (int*)alloc((size_t)EPE * 4);
    int* row_ptr  = (int*)alloc((size_t)(NN + 1) * 4);
    int* degcur   = (int*)alloc((size_t)2 * NN * 4);
    int* deg = degcur, * cursor = degcur + NN;

    hipMemsetAsync(degcur, 0, 2 * NN * sizeof(int), stream);

    int eb = (EPE + 255) / 256;
    build_edges_kernel<<<eb, 256, 0, stream>>>(ei, src_all, dst_all, deg);
    scan_kernel<<<1, 1024, 0, stream>>>(deg, row_ptr, NN);
    scatter_kernel<<<eb, 256, 0, stream>>>(src_all, dst_all, row_ptr, cursor, col_src, col_eid);

    {
        int npad = NN * 32 + (MPAD - NN) * 832;
        padA_kernel<<<(npad + 255) / 256, 256, 0, stream>>>(Ap);
    }
    {
        size_t na = (size_t)MPAD * 256;
        convA_kernel<<<(int)((na + 255) / 256), 256, 0, stream>>>(X, 200, 200, 256, Ap0);
    }
    convB_all_kernel<<<dim3((896 * 832 + 255) / 256, 5), 256, 0, stream>>>(
        (const float*)d_in[2], (const float*)d_in[6], (const float*)d_in[10],
        (const float*)d_in[14], (const float*)d_in[18], Bp);

    for (int i = 0; i < 5; ++i) {
        int H   = (i == 4) ? 1 : 4;
        int HC  = H * CC;
        int Kp  = (i == 0) ? 256 : 832;
        int Np  = (i == 4) ? 256 : 896;
        int ncol = Np / 128;
        const unsigned short* Acur = (i == 0) ? Ap0 : Ap;
        const unsigned short* Bpl = Bp + (size_t)i * (896 * 832);
        const float* as_ = (const float*)d_in[3 + 4 * i];
        const float* ad_ = (const float*)d_in[4 + 4 * i];
        const float* b_  = (const float*)d_in[5 + 4 * i];
        float* asrc_l = attn_all + (size_t)i * 2 * NN * 4;
        float* adst_l = asrc_l + NN * 4;

        gemm_mfma<<<ncol * (MPAD / 64), 256, 0, stream>>>(Acur, Bpl, hbuf, as_, ad_,
                                                          g_as, g_ad, Kp, Np, ncol, HC, H);

        fold_attn_kernel<<<(NN * H + 255) / 256, 256, 0, stream>>>(g_as, g_ad,
                                                                   asrc_l, adst_l, H);

        float* out32 = (i == 4) ? (float*)d_out : nullptr;
        unsigned short* apn = (i == 4) ? nullptr : Ap;
        float* wout = (i == 4) ? (float*)d_out + (size_t)NN * CC : nullptr;
        fused_agg_kernel<<<NN, 256, 0, stream>>>(hbuf, asrc_l, adst_l, row_ptr, col_src,
                                                 col_eid, b_, out32, apn, wout, H, HC, Np);
    }
}

// Round 10
// 544.222 us; speedup vs baseline: 1.0505x; 1.0505x over previous
//
#include <hip/hip_runtime.h>
#include <math.h>

#define NN 10000
#define EE 100000
#define EPE 110000   // edges + self loops
#define CC 200
#define MPAD 10112   // 158 * 64

typedef __attribute__((ext_vector_type(8))) _Float16 f16x8;
typedef __attribute__((ext_vector_type(4))) _Float16 f16x4;
typedef __attribute__((ext_vector_type(4))) unsigned short u16x4;
typedef __attribute__((ext_vector_type(4))) float f32x4;

__device__ __forceinline__ float lrelu(float v) { return v >= 0.f ? v : 0.2f * v; }
__device__ __forceinline__ float gelu_f(float v) { return 0.5f * v * (1.f + erff(v * 0.70710678118654752f)); }

// ---------------- CSR build ----------------

__global__ void build_edges_kernel(const int* __restrict__ ei,
                                   int* __restrict__ src_all, int* __restrict__ dst_all,
                                   int* __restrict__ deg) {
    int e = blockIdx.x * blockDim.x + threadIdx.x;
    if (e >= EPE) return;
    int s, d;
    if (e < EE) { s = ei[e]; d = ei[EE + e]; }
    else        { s = e - EE; d = e - EE; }
    src_all[e] = s;
    dst_all[e] = d;
    atomicAdd(&deg[d], 1);
}

__global__ void scan_kernel(const int* __restrict__ deg, int* __restrict__ row_ptr, int n) {
    __shared__ int wsum[16];
    int tid = threadIdx.x;
    int lane = tid & 63, w = tid >> 6;
    int carry = 0;
    for (int base = 0; base < n; base += 1024) {
        int idx = base + tid;
        int v = (idx < n) ? deg[idx] : 0;
        int x = v;
#pragma unroll
        for (int off = 1; off < 64; off <<= 1) {
            int t = __shfl_up(x, off);
            if (lane >= off) x += t;
        }
        if (lane == 63) wsum[w] = x;
        __syncthreads();
        if (w == 0) {
            int s = (lane < 16) ? wsum[lane] : 0;
#pragma unroll
            for (int off = 1; off < 16; off <<= 1) {
                int t = __shfl_up(s, off);
                if (lane >= off) s += t;
            }
            if (lane < 16) wsum[lane] = s;
        }
        __syncthreads();
        int woff = (w > 0) ? wsum[w - 1] : 0;
        if (idx < n) row_ptr[idx] = carry + woff + x - v;   // exclusive
        carry += wsum[15];
        __syncthreads();
    }
    if (tid == 0) row_ptr[n] = carry;
}

__global__ void scatter_kernel(const int* __restrict__ src_all, const int* __restrict__ dst_all,
                               const int* __restrict__ row_ptr, int* __restrict__ cursor,
                               int* __restrict__ col_src, int* __restrict__ col_eid) {
    int e = blockIdx.x * blockDim.x + threadIdx.x;
    if (e >= EPE) return;
    int d = dst_all[e];
    int pos = row_ptr[d] + atomicAdd(&cursor[d], 1);
    col_src[pos] = src_all[e];
    col_eid[pos] = e;
}

// ---------------- fp16 conversion ----------------

__global__ void convA_kernel(const float* __restrict__ x, int sx, int Fin, int Kp,
                             unsigned short* __restrict__ Ap) {
    size_t idx = (size_t)blockIdx.x * 256 + threadIdx.x;
    if (idx >= (size_t)MPAD * Kp) return;
    int row = (int)(idx / Kp);
    int kk  = (int)(idx % Kp);
    float v = 0.f;
    if (row < NN && kk < Fin) v = x[(size_t)row * sx + kk];
    Ap[idx] = __builtin_bit_cast(unsigned short, (_Float16)v);
}

// zero only the pad regions of Ap [MPAD][832] (agg writes rows<NN, cols<800)
__global__ void padA_kernel(unsigned short* __restrict__ Ap) {
    int idx = blockIdx.x * 256 + threadIdx.x;
    if (idx < NN * 32) {
        int rw = idx >> 5, c = idx & 31;
        Ap[(size_t)rw * 832 + 800 + c] = 0;
    } else {
        int j = idx - NN * 32;
        if (j < (MPAD - NN) * 832) {
            int rw = j / 832, c = j - rw * 832;
            Ap[(size_t)(NN + rw) * 832 + c] = 0;
        }
    }
}

// all 5 layers' B' (transposed [n][k]) in one dispatch; slot stride 896*832
__global__ void convB_all_kernel(const float* __restrict__ W0, const float* __restrict__ W1,
                                 const float* __restrict__ W2, const float* __restrict__ W3,
                                 const float* __restrict__ W4,
                                 unsigned short* __restrict__ Bp) {
    int l = blockIdx.y;
    const float* W = (l == 0) ? W0 : (l == 1) ? W1 : (l == 2) ? W2 : (l == 3) ? W3 : W4;
    int Fin = (l == 0) ? 200 : 800;
    int HC  = (l == 4) ? 200 : 800;
    int Kp  = (l == 0) ? 256 : 832;
    int Np  = (l == 4) ? 256 : 896;
    int idx = blockIdx.x * 256 + threadIdx.x;
    if (idx >= Np * Kp) return;
    int n = idx / Kp, kk = idx - n * Kp;
    float v = 0.f;
    if (n < HC && kk < Fin) v = W[(size_t)kk * HC + n];
    Bp[(size_t)l * (896 * 832) + idx] = __builtin_bit_cast(unsigned short, (_Float16)v);
}

// ---------------- MFMA GEMM + attention-score partials ----------------
// 64x64 tile, BK=64, 4 waves (2x2, per-wave 32x32), 16x16x32 f16 MFMA,
// global_load_lds w16, XOR chunk swizzle via pre-swizzled source,
// XCD-bijective block swizzle, 2-phase dbuf counted vmcnt(4).
// LDS = 32 KB -> 5 blocks/CU (20 waves/CU): TLP is the latency-hiding lever.

__global__ __launch_bounds__(256) void gemm_mfma(const unsigned short* __restrict__ A,
                                                 const unsigned short* __restrict__ B,
                                                 unsigned short* __restrict__ C,
                                                 const float* __restrict__ a_s,
                                                 const float* __restrict__ a_d,
                                                 float* __restrict__ g_as,
                                                 float* __restrict__ g_ad,
                                                 int Kt, int Np, int ncol, int HC, int H) {
    __shared__ unsigned short As[2][4096];   // 2 x 8 KB (64 rows x 64 k)
    __shared__ unsigned short Bs[2][4096];   // 2 x 8 KB (64 n-rows x 64 k)

    int tid = threadIdx.x;
    int lane = tid & 63, wave = tid >> 6;

    int nwg = gridDim.x;
    int orig = blockIdx.x;
    int q = nwg >> 3, r = nwg & 7;
    int xcd = orig & 7, sidx = orig >> 3;
    int wg = (xcd < r ? xcd * (q + 1) : r * (q + 1) + (xcd - r) * q) + sidx;
    int rowT = wg / ncol, colT = wg - rowT * ncol;
    int row0 = rowT * 64, col0 = colT * 64;
    int wr = wave >> 1, wc = wave & 1;

    size_t gAoff[2], gBoff[2];
    int ldsSeg[2];
#pragma unroll
    for (int i = 0; i < 2; ++i) {
        int seg = wave * 2 + i;            // 0..7
        int chunkIdx = seg * 64 + lane;    // 0..511
        int rr = chunkIdx >> 3;            // row 0..63
        int c = chunkIdx & 7;
        int cg = c ^ (rr & 7);             // pre-swizzled source chunk
        gAoff[i] = (size_t)(row0 + rr) * Kt + (size_t)cg * 8;
        gBoff[i] = (size_t)(col0 + rr) * Kt + (size_t)cg * 8;
        ldsSeg[i] = seg * 512;
    }

    int rowA[2], rowB[2];
#pragma unroll
    for (int m = 0; m < 2; ++m) rowA[m] = wr * 32 + m * 16 + (lane & 15);
#pragma unroll
    for (int n = 0; n < 2; ++n) rowB[n] = wc * 32 + n * 16 + (lane & 15);

    // hoisted LDS read offsets
    int iaOff[2][2], ibOff[2][2];
#pragma unroll
    for (int kh = 0; kh < 2; ++kh) {
        int cw = kh * 4 + (lane >> 4);
#pragma unroll
        for (int m = 0; m < 2; ++m)
            iaOff[kh][m] = rowA[m] * 64 + ((cw ^ (rowA[m] & 7)) << 3);
#pragma unroll
        for (int n = 0; n < 2; ++n)
            ibOff[kh][n] = rowB[n] * 64 + ((cw ^ (rowB[n] & 7)) << 3);
    }

    f32x4 acc[2][2];
#pragma unroll
    for (int m = 0; m < 2; ++m)
#pragma unroll
        for (int n = 0; n < 2; ++n) acc[m][n] = f32x4{0.f, 0.f, 0.f, 0.f};

#define STAGE(bufi, kk)                                                                     \
    _Pragma("unroll")                                                                       \
    for (int i = 0; i < 2; ++i) {                                                           \
        __builtin_amdgcn_global_load_lds(                                                   \
            (const __attribute__((address_space(1))) void*)(A + gAoff[i] + (kk)),           \
            (__attribute__((address_space(3))) void*)(&As[bufi][ldsSeg[i]]), 16, 0, 0);     \
        __builtin_amdgcn_global_load_lds(                                                   \
            (const __attribute__((address_space(1))) void*)(B + gBoff[i] + (kk)),           \
            (__attribute__((address_space(3))) void*)(&Bs[bufi][ldsSeg[i]]), 16, 0, 0);     \
    }

    int nk = Kt >> 6;
    STAGE(0, 0)

    for (int t = 0; t < nk; ++t) {
        int cur = t & 1;
        if (t + 1 < nk) {
            STAGE(1 - cur, (t + 1) * 64)
            asm volatile("s_waitcnt vmcnt(4)" ::: "memory");   // current tile's 4 loads done
        } else {
            asm volatile("s_waitcnt vmcnt(0)" ::: "memory");
        }
        __builtin_amdgcn_s_barrier();
        __builtin_amdgcn_sched_barrier(0);

        const unsigned short* asb = As[cur];
        const unsigned short* bsb = Bs[cur];
#pragma unroll
        for (int kh = 0; kh < 2; ++kh) {
            f16x8 a[2], b[2];
#pragma unroll
            for (int m = 0; m < 2; ++m) a[m] = *(const f16x8*)(&asb[iaOff[kh][m]]);
#pragma unroll
            for (int n = 0; n < 2; ++n) b[n] = *(const f16x8*)(&bsb[ibOff[kh][n]]);
            if (kh == 0) __builtin_amdgcn_s_setprio(1);
#pragma unroll
            for (int m = 0; m < 2; ++m)
#pragma unroll
                for (int n = 0; n < 2; ++n)
                    acc[m][n] = __builtin_amdgcn_mfma_f32_16x16x32_f16(a[m], b[n], acc[m][n], 0, 0, 0);
        }
        __builtin_amdgcn_s_setprio(0);
        asm volatile("s_waitcnt lgkmcnt(0)" ::: "memory");
        __builtin_amdgcn_sched_barrier(0);
        __builtin_amdgcn_s_barrier();
        __builtin_amdgcn_sched_barrier(0);
    }
#undef STAGE

    int crow = row0 + wr * 32 + ((lane >> 4) << 2);
    int ccol = col0 + wc * 32 + (lane & 15);
#pragma unroll
    for (int m = 0; m < 2; ++m)
#pragma unroll
        for (int j = 0; j < 4; ++j) {
            size_t rb = (size_t)(crow + m * 16 + j) * Np;
#pragma unroll
            for (int n = 0; n < 2; ++n)
                C[rb + ccol + n * 16] =
                    __builtin_bit_cast(unsigned short, (_Float16)acc[m][n][j]);
        }

    // ---- attention-score partials (no atomics; 32-col window per wave) ----
    int base = col0 + wc * 32;      // wave-uniform
    int hA = base / CC;
    float sAs[2][8], sAd[2][8];
#pragma unroll
    for (int b = 0; b < 2; ++b)
#pragma unroll
        for (int k = 0; k < 8; ++k) { sAs[b][k] = 0.f; sAd[b][k] = 0.f; }
#pragma unroll
    for (int n = 0; n < 2; ++n) {
        int c = ccol + n * 16;
        if (c < HC) {
            int hd = c / CC;
            int cm = c - hd * CC;
            float asv = a_s[hd * CC + cm];
            float adv = a_d[hd * CC + cm];
            int b = hd - hA;
#pragma unroll
            for (int m = 0; m < 2; ++m)
#pragma unroll
                for (int j = 0; j < 4; ++j) {
                    sAs[b][m * 4 + j] += acc[m][n][j] * asv;
                    sAd[b][m * 4 + j] += acc[m][n][j] * adv;
                }
        }
    }
#pragma unroll
    for (int off = 1; off < 16; off <<= 1) {
#pragma unroll
        for (int b = 0; b < 2; ++b)
#pragma unroll
            for (int k = 0; k < 8; ++k) {
                sAs[b][k] += __shfl_xor(sAs[b][k], off);
                sAd[b][k] += __shfl_xor(sAd[b][k], off);
            }
    }
    if ((lane & 15) == 0) {
        int slice = colT * 2 + wc;
        float* pas = g_as + (size_t)slice * NN * H;
        float* pad2 = g_ad + (size_t)slice * NN * H;
#pragma unroll
        for (int b = 0; b < 2; ++b) {
            int hd = hA + b;
            if (hd >= H) continue;
#pragma unroll
            for (int m = 0; m < 2; ++m)
#pragma unroll
                for (int j = 0; j < 4; ++j) {
                    int row = crow + m * 16 + j;
                    if (row < NN) {
                        pas[row * H + hd] = sAs[b][m * 4 + j];
                        pad2[row * H + hd] = sAd[b][m * 4 + j];
                    }
                }
        }
    }
}

// fold per-window partials into final asrc/adst (static window<->head overlap; 32-col windows)
__global__ void fold_attn_kernel(const float* __restrict__ g_as, const float* __restrict__ g_ad,
                                 float* __restrict__ asrc, float* __restrict__ adst, int H) {
    int i = blockIdx.x * 256 + threadIdx.x;
    if (i >= NN * H) return;
    int hd = i % H;
    int w0 = (CC * hd) >> 5, w1 = (CC * hd + CC - 1) >> 5;
    float sa = 0.f, sd = 0.f;
    for (int w = w0; w <= w1; ++w) {
        sa += g_as[(size_t)w * NN * H + i];
        sd += g_ad[(size_t)w * NN * H + i];
    }
    asrc[i] = sa;
    adst[i] = sd;
}

// ---------------- fused softmax(m/den) + weights + aggregation + bias + gelu ----------------

__global__ __launch_bounds__(256) void fused_agg_kernel(const unsigned short* __restrict__ h,
                                                        const float* __restrict__ asrc,
                                                        const float* __restrict__ adst,
                                                        const int* __restrict__ row_ptr,
                                                        const int* __restrict__ col_src,
                                                        const int* __restrict__ col_eid,
                                                        const float* __restrict__ bias,
                                                        float* __restrict__ out32,
                                                        unsigned short* __restrict__ apn,
                                                        float* __restrict__ wout,
                                                        int H, int HC, int HCp) {
    int n = blockIdx.x;
    int tid = threadIdx.x;
    int wave = tid >> 6, lane = tid & 63;
    int beg = row_ptr[n], end = row_ptr[n + 1];

    __shared__ float m_s[4], inv_s[4], ad_s[4];
    __shared__ float w_lds[64 * 4];
    __shared__ int src_lds[64];

    if (wave < H) {
        float ad = adst[n * H + wave];
        float m = -1e30f, den = 0.f;
        for (int e = beg + lane; e < end; e += 64) {
            float v = lrelu(asrc[col_src[e] * H + wave] + ad);
            if (v > m) { den = den * expf(m - v) + 1.f; m = v; }
            else den += expf(v - m);
        }
#pragma unroll
        for (int off = 1; off < 64; off <<= 1) {
            float m2 = __shfl_xor(m, off);
            float d2 = __shfl_xor(den, off);
            float M = fmaxf(m, m2);
            den = den * expf(m - M) + d2 * expf(m2 - M);
            m = M;
        }
        if (lane == 0) { m_s[wave] = m; inv_s[wave] = 1.f / den; ad_s[wave] = ad; }
    }
    __syncthreads();

    int ch0 = tid * 4;
    int head = ch0 / CC;
    float a0 = 0.f, a1 = 0.f, a2 = 0.f, a3 = 0.f;

    for (int c0 = beg; c0 < end; c0 += 64) {
        int cnt = min(64, end - c0);
        if (wave < H && lane < cnt) {
            int e = c0 + lane;
            int s = col_src[e];
            float v = lrelu(asrc[s * H + wave] + ad_s[wave]);
            float wv = expf(v - m_s[wave]) * inv_s[wave];
            w_lds[lane * 4 + wave] = wv;
            if (wave == 0) src_lds[lane] = s;
            if (wout) wout[(size_t)col_eid[e] * H + wave] = wv;
        }
        __syncthreads();
        if (ch0 < HC) {
            // 2-deep prefetch pipeline
            f16x4 hva = {}, hvb = {};
            hva = *(const f16x4*)(h + (size_t)src_lds[0] * HCp + ch0);
            if (cnt > 1) hvb = *(const f16x4*)(h + (size_t)src_lds[1] * HCp + ch0);
            for (int j = 0; j < cnt; ++j) {
                f16x4 hvc = {};
                if (j + 2 < cnt) hvc = *(const f16x4*)(h + (size_t)src_lds[j + 2] * HCp + ch0);
                float wv = w_lds[j * 4 + head];
                a0 += wv * (float)hva[0];
                a1 += wv * (float)hva[1];
                a2 += wv * (float)hva[2];
                a3 += wv * (float)hva[3];
                hva = hvb; hvb = hvc;
            }
        }
        __syncthreads();
    }

    if (ch0 < HC) {
        float4 bv = *(const float4*)(bias + ch0);
        float g0 = gelu_f(a0 + bv.x), g1 = gelu_f(a1 + bv.y);
        float g2 = gelu_f(a2 + bv.z), g3 = gelu_f(a3 + bv.w);
        if (out32) {
            *(float4*)(out32 + (size_t)n * HC + ch0) = float4{g0, g1, g2, g3};
        } else {
            *(u16x4*)(apn + (size_t)n * 832 + ch0) = u16x4{
                __builtin_bit_cast(unsigned short, (_Float16)g0),
                __builtin_bit_cast(unsigned short, (_Float16)g1),
                __builtin_bit_cast(unsigned short, (_Float16)g2),
                __builtin_bit_cast(unsigned short, (_Float16)g3)};
        }
    }
}

// ---------------- host ----------------

extern "C" void kernel_launch(void* const* d_in, const int* in_sizes, int n_in,
                              void* d_out, int out_size, void* d_ws, size_t ws_size,
                              hipStream_t stream) {
    const float* X = (const float*)d_in[0];
    const int* ei = (const int*)d_in[1];

    char* ws = (char*)d_ws;
    size_t off = 0;
    auto alloc = [&](size_t bytes) { void* p = ws + off; off += (bytes + 255) & ~(size_t)255; return p; };

    unsigned short* Ap0 = (unsigned short*)alloc((size_t)MPAD * 256 * 2);       // 5.2 MB
    unsigned short* Ap  = (unsigned short*)alloc((size_t)MPAD * 832 * 2);       // 16.8 MB
    unsigned short* Bp  = (unsigned short*)alloc((size_t)5 * 896 * 832 * 2);    // 7.5 MB
    unsigned short* hbuf= (unsigned short*)alloc((size_t)MPAD * 896 * 2);       // 18.1 MB
    float* g_as  = (float*)alloc((size_t)28 * NN * 4 * 4);                      // 4.48 MB
    float* g_ad  = (float*)alloc((size_t)28 * NN * 4 * 4);                      // 4.48 MB
    float* attn_all = (float*)alloc((size_t)5 * 2 * NN * 4 * 4);                // 1.6 MB
    int* src_all  = (int*)alloc((size_t)EPE * 4);
    int* dst_all  = (int*)alloc((size_t)EPE * 4);
    int* col_src  = (int*)alloc((size_t)EPE * 4);
    int* col_eid  = (int*)alloc((size_t)EPE * 4);
    int* row_ptr  = (int*)alloc((size_t)(NN + 1) * 4);
    int* degcur   = (int*)alloc((size_t)2 * NN * 4);
    int* deg = degcur, * cursor = degcur + NN;

    hipMemsetAsync(degcur, 0, 2 * NN * sizeof(int), stream);

    int eb = (EPE + 255) / 256;
    build_edges_kernel<<<eb, 256, 0, stream>>>(ei, src_all, dst_all, deg);
    scan_kernel<<<1, 1024, 0, stream>>>(deg, row_ptr, NN);
    scatter_kernel<<<eb, 256, 0, stream>>>(src_all, dst_all, row_ptr, cursor, col_src, col_eid);

    {
        int npad = NN * 32 + (MPAD - NN) * 832;
        padA_kernel<<<(npad + 255) / 256, 256, 0, stream>>>(Ap);
    }
    {
        size_t na = (size_t)MPAD * 256;
        convA_kernel<<<(int)((na + 255) / 256), 256, 0, stream>>>(X, 200, 200, 256, Ap0);
    }
    convB_all_kernel<<<dim3((896 * 832 + 255) / 256, 5), 256, 0, stream>>>(
        (const float*)d_in[2], (const float*)d_in[6], (const float*)d_in[10],
        (const float*)d_in[14], (const float*)d_in[18], Bp);

    for (int i = 0; i < 5; ++i) {
        int H   = (i == 4) ? 1 : 4;
        int HC  = H * CC;
        int Kp  = (i == 0) ? 256 : 832;
        int Np  = (i == 4) ? 256 : 896;
        int ncol = Np / 64;
        const unsigned short* Acur = (i == 0) ? Ap0 : Ap;
        const unsigned short* Bpl = Bp + (size_t)i * (896 * 832);
        const float* as_ = (const float*)d_in[3 + 4 * i];
        const float* ad_ = (const float*)d_in[4 + 4 * i];
        const float* b_  = (const float*)d_in[5 + 4 * i];
        float* asrc_l = attn_all + (size_t)i * 2 * NN * 4;
        float* adst_l = asrc_l + NN * 4;

        gemm_mfma<<<ncol * (MPAD / 64), 256, 0, stream>>>(Acur, Bpl, hbuf, as_, ad_,
                                                          g_as, g_ad, Kp, Np, ncol, HC, H);

        fold_attn_kernel<<<(NN * H + 255) / 256, 256, 0, stream>>>(g_as, g_ad,
                                                                   asrc_l, adst_l, H);

        float* out32 = (i == 4) ? (float*)d_out : nullptr;
        unsigned short* apn = (i == 4) ? nullptr : Ap;
        float* wout = (i == 4) ? (float*)d_out + (size_t)NN * CC : nullptr;
        fused_agg_kernel<<<NN, 256, 0, stream>>>(hbuf, asrc_l, adst_l, row_ptr, col_src,
                                                 col_eid, b_, out32, apn, wout, H, HC, Np);
    }
}

// Round 11
// 460.376 us; speedup vs baseline: 1.2419x; 1.1821x over previous
//
#include <hip/hip_runtime.h>
#include <math.h>

#define NN 10000
#define EE 100000
#define EPE 110000   // edges + self loops
#define CC 200
#define MPAD 10112   // 79 * 128

typedef __attribute__((ext_vector_type(8))) _Float16 f16x8;
typedef __attribute__((ext_vector_type(4))) _Float16 f16x4;
typedef __attribute__((ext_vector_type(4))) unsigned short u16x4;
typedef __attribute__((ext_vector_type(4))) float f32x4;

__device__ __forceinline__ float lrelu(float v) { return v >= 0.f ? v : 0.2f * v; }
__device__ __forceinline__ float gelu_f(float v) { return 0.5f * v * (1.f + erff(v * 0.70710678118654752f)); }

// ---------------- CSR build ----------------

__global__ void build_edges_kernel(const int* __restrict__ ei,
                                   int* __restrict__ src_all, int* __restrict__ dst_all,
                                   int* __restrict__ deg) {
    int e = blockIdx.x * blockDim.x + threadIdx.x;
    if (e >= EPE) return;
    int s, d;
    if (e < EE) { s = ei[e]; d = ei[EE + e]; }
    else        { s = e - EE; d = e - EE; }
    src_all[e] = s;
    dst_all[e] = d;
    atomicAdd(&deg[d], 1);
}

__global__ void scan_kernel(const int* __restrict__ deg, int* __restrict__ row_ptr, int n) {
    __shared__ int wsum[16];
    int tid = threadIdx.x;
    int lane = tid & 63, w = tid >> 6;
    int carry = 0;
    for (int base = 0; base < n; base += 1024) {
        int idx = base + tid;
        int v = (idx < n) ? deg[idx] : 0;
        int x = v;
#pragma unroll
        for (int off = 1; off < 64; off <<= 1) {
            int t = __shfl_up(x, off);
            if (lane >= off) x += t;
        }
        if (lane == 63) wsum[w] = x;
        __syncthreads();
        if (w == 0) {
            int s = (lane < 16) ? wsum[lane] : 0;
#pragma unroll
            for (int off = 1; off < 16; off <<= 1) {
                int t = __shfl_up(s, off);
                if (lane >= off) s += t;
            }
            if (lane < 16) wsum[lane] = s;
        }
        __syncthreads();
        int woff = (w > 0) ? wsum[w - 1] : 0;
        if (idx < n) row_ptr[idx] = carry + woff + x - v;   // exclusive
        carry += wsum[15];
        __syncthreads();
    }
    if (tid == 0) row_ptr[n] = carry;
}

__global__ void scatter_kernel(const int* __restrict__ src_all, const int* __restrict__ dst_all,
                               const int* __restrict__ row_ptr, int* __restrict__ cursor,
                               int* __restrict__ col_src, int* __restrict__ col_eid) {
    int e = blockIdx.x * blockDim.x + threadIdx.x;
    if (e >= EPE) return;
    int d = dst_all[e];
    int pos = row_ptr[d] + atomicAdd(&cursor[d], 1);
    col_src[pos] = src_all[e];
    col_eid[pos] = e;
}

// ---------------- fp16 conversion ----------------

__global__ void convA_kernel(const float* __restrict__ x, int sx, int Fin, int Kp,
                             unsigned short* __restrict__ Ap) {
    size_t idx = (size_t)blockIdx.x * 256 + threadIdx.x;
    if (idx >= (size_t)MPAD * Kp) return;
    int row = (int)(idx / Kp);
    int kk  = (int)(idx % Kp);
    float v = 0.f;
    if (row < NN && kk < Fin) v = x[(size_t)row * sx + kk];
    Ap[idx] = __builtin_bit_cast(unsigned short, (_Float16)v);
}

// zero only the pad regions of Ap [MPAD][832] (agg writes rows<NN, cols<800)
__global__ void padA_kernel(unsigned short* __restrict__ Ap) {
    int idx = blockIdx.x * 256 + threadIdx.x;
    if (idx < NN * 32) {
        int rw = idx >> 5, c = idx & 31;
        Ap[(size_t)rw * 832 + 800 + c] = 0;
    } else {
        int j = idx - NN * 32;
        if (j < (MPAD - NN) * 832) {
            int rw = j / 832, c = j - rw * 832;
            Ap[(size_t)(NN + rw) * 832 + c] = 0;
        }
    }
}

// all 5 layers' B' (transposed [n][k]) in one dispatch; slot stride 896*832
__global__ void convB_all_kernel(const float* __restrict__ W0, const float* __restrict__ W1,
                                 const float* __restrict__ W2, const float* __restrict__ W3,
                                 const float* __restrict__ W4,
                                 unsigned short* __restrict__ Bp) {
    int l = blockIdx.y;
    const float* W = (l == 0) ? W0 : (l == 1) ? W1 : (l == 2) ? W2 : (l == 3) ? W3 : W4;
    int Fin = (l == 0) ? 200 : 800;
    int HC  = (l == 4) ? 200 : 800;
    int Kp  = (l == 0) ? 256 : 832;
    int Np  = (l == 4) ? 256 : 896;
    int idx = blockIdx.x * 256 + threadIdx.x;
    if (idx >= Np * Kp) return;
    int n = idx / Kp, kk = idx - n * Kp;
    float v = 0.f;
    if (n < HC && kk < Fin) v = W[(size_t)kk * HC + n];
    Bp[(size_t)l * (896 * 832) + idx] = __builtin_bit_cast(unsigned short, (_Float16)v);
}

// ---------------- MFMA GEMM (round-4 structure: 128x128, single buffer) ----------------
// C[MPAD x Np](fp16) = A[MPAD x K] * B[Np x K]^T; 4 waves 2x2, per-wave 64x64,
// 16x16x32 f16 MFMA, global_load_lds w16, XOR chunk swizzle via pre-swizzled
// source, XCD-bijective block swizzle, plain __syncthreads. No epilogue.

__global__ __launch_bounds__(256) void gemm_mfma(const unsigned short* __restrict__ A,
                                                 const unsigned short* __restrict__ B,
                                                 unsigned short* __restrict__ C,
                                                 int Kt, int Np, int ncol) {
    __shared__ unsigned short As[8192];   // [128 rows][64 k] swizzled, 16 KB
    __shared__ unsigned short Bs[8192];

    int tid = threadIdx.x;
    int lane = tid & 63, wave = tid >> 6;

    int nwg = gridDim.x;
    int orig = blockIdx.x;
    int q = nwg >> 3, r = nwg & 7;
    int xcd = orig & 7, sidx = orig >> 3;
    int wg = (xcd < r ? xcd * (q + 1) : r * (q + 1) + (xcd - r) * q) + sidx;
    int rowT = wg / ncol, colT = wg - rowT * ncol;
    int row0 = rowT * 128, col0 = colT * 128;
    int wr = wave >> 1, wc = wave & 1;

    size_t gAoff[4], gBoff[4];
    int ldsSeg[4];
#pragma unroll
    for (int i = 0; i < 4; ++i) {
        int seg = wave * 4 + i;            // 0..15
        int chunkIdx = seg * 64 + lane;    // 0..1023
        int rr = chunkIdx >> 3;            // row 0..127
        int c = chunkIdx & 7;
        int cg = c ^ (rr & 7);             // pre-swizzled source chunk
        gAoff[i] = (size_t)(row0 + rr) * Kt + (size_t)cg * 8;
        gBoff[i] = (size_t)(col0 + rr) * Kt + (size_t)cg * 8;
        ldsSeg[i] = seg * 512;
    }

    int rowA[4], rowB[4];
#pragma unroll
    for (int m = 0; m < 4; ++m) {
        rowA[m] = wr * 64 + m * 16 + (lane & 15);
        rowB[m] = wc * 64 + m * 16 + (lane & 15);
    }

    // hoisted LDS read offsets
    int iaOff[2][4], ibOff[2][4];
#pragma unroll
    for (int kh = 0; kh < 2; ++kh) {
        int cw = kh * 4 + (lane >> 4);
#pragma unroll
        for (int m = 0; m < 4; ++m)
            iaOff[kh][m] = rowA[m] * 64 + ((cw ^ (rowA[m] & 7)) << 3);
#pragma unroll
        for (int n = 0; n < 4; ++n)
            ibOff[kh][n] = rowB[n] * 64 + ((cw ^ (rowB[n] & 7)) << 3);
    }

    f32x4 acc[4][4];
#pragma unroll
    for (int m = 0; m < 4; ++m)
#pragma unroll
        for (int n = 0; n < 4; ++n) acc[m][n] = f32x4{0.f, 0.f, 0.f, 0.f};

    for (int k0 = 0; k0 < Kt; k0 += 64) {
#pragma unroll
        for (int i = 0; i < 4; ++i) {
            __builtin_amdgcn_global_load_lds(
                (const __attribute__((address_space(1))) void*)(A + gAoff[i] + k0),
                (__attribute__((address_space(3))) void*)(&As[ldsSeg[i]]), 16, 0, 0);
            __builtin_amdgcn_global_load_lds(
                (const __attribute__((address_space(1))) void*)(B + gBoff[i] + k0),
                (__attribute__((address_space(3))) void*)(&Bs[ldsSeg[i]]), 16, 0, 0);
        }
        __syncthreads();

#pragma unroll
        for (int kh = 0; kh < 2; ++kh) {
            f16x8 a[4], b[4];
#pragma unroll
            for (int m = 0; m < 4; ++m) a[m] = *(const f16x8*)(&As[iaOff[kh][m]]);
#pragma unroll
            for (int n = 0; n < 4; ++n) b[n] = *(const f16x8*)(&Bs[ibOff[kh][n]]);
#pragma unroll
            for (int m = 0; m < 4; ++m)
#pragma unroll
                for (int n = 0; n < 4; ++n)
                    acc[m][n] = __builtin_amdgcn_mfma_f32_16x16x32_f16(a[m], b[n], acc[m][n], 0, 0, 0);
        }
        __syncthreads();
    }

    int crow = row0 + wr * 64 + ((lane >> 4) << 2);
    int ccol = col0 + wc * 64 + (lane & 15);
#pragma unroll
    for (int m = 0; m < 4; ++m)
#pragma unroll
        for (int j = 0; j < 4; ++j) {
            size_t rb = (size_t)(crow + m * 16 + j) * Np;
#pragma unroll
            for (int n = 0; n < 4; ++n)
                C[rb + ccol + n * 16] =
                    __builtin_bit_cast(unsigned short, (_Float16)acc[m][n][j]);
        }
}

// ---------------- attention scores (vectorized fp16 h) ----------------

__global__ void attn_kernel(const unsigned short* __restrict__ h,
                            const float* __restrict__ a_s, const float* __restrict__ a_d,
                            float* __restrict__ asrc, float* __restrict__ adst,
                            int H, int HCp) {
    int n = blockIdx.x;
    int wave = threadIdx.x >> 6;
    int lane = threadIdx.x & 63;
    if (wave >= H) return;
    float sa = 0.f, da = 0.f;
    int c0 = lane * 4;
    if (c0 < CC) {
        f16x4 hv = *(const f16x4*)(h + (size_t)n * HCp + wave * CC + c0);
        float4 av = *(const float4*)(a_s + wave * CC + c0);
        float4 dv = *(const float4*)(a_d + wave * CC + c0);
        float h0 = (float)hv[0], h1 = (float)hv[1], h2 = (float)hv[2], h3 = (float)hv[3];
        sa = h0 * av.x + h1 * av.y + h2 * av.z + h3 * av.w;
        da = h0 * dv.x + h1 * dv.y + h2 * dv.z + h3 * dv.w;
    }
#pragma unroll
    for (int off = 32; off > 0; off >>= 1) {
        sa += __shfl_down(sa, off);
        da += __shfl_down(da, off);
    }
    if (lane == 0) {
        asrc[n * H + wave] = sa;
        adst[n * H + wave] = da;
    }
}

// ---------------- fused softmax(m/den) + weights + aggregation + bias + gelu ----------------

__global__ __launch_bounds__(256) void fused_agg_kernel(const unsigned short* __restrict__ h,
                                                        const float* __restrict__ asrc,
                                                        const float* __restrict__ adst,
                                                        const int* __restrict__ row_ptr,
                                                        const int* __restrict__ col_src,
                                                        const int* __restrict__ col_eid,
                                                        const float* __restrict__ bias,
                                                        float* __restrict__ out32,
                                                        unsigned short* __restrict__ apn,
                                                        float* __restrict__ wout,
                                                        int H, int HC, int HCp) {
    int n = blockIdx.x;
    int tid = threadIdx.x;
    int wave = tid >> 6, lane = tid & 63;
    int beg = row_ptr[n], end = row_ptr[n + 1];

    __shared__ float m_s[4], inv_s[4], ad_s[4];
    __shared__ float w_lds[64 * 4];
    __shared__ int src_lds[64];

    if (wave < H) {
        float ad = adst[n * H + wave];
        float m = -1e30f, den = 0.f;
        for (int e = beg + lane; e < end; e += 64) {
            float v = lrelu(asrc[col_src[e] * H + wave] + ad);
            if (v > m) { den = den * expf(m - v) + 1.f; m = v; }
            else den += expf(v - m);
        }
#pragma unroll
        for (int off = 1; off < 64; off <<= 1) {
            float m2 = __shfl_xor(m, off);
            float d2 = __shfl_xor(den, off);
            float M = fmaxf(m, m2);
            den = den * expf(m - M) + d2 * expf(m2 - M);
            m = M;
        }
        if (lane == 0) { m_s[wave] = m; inv_s[wave] = 1.f / den; ad_s[wave] = ad; }
    }
    __syncthreads();

    int ch0 = tid * 4;
    int head = ch0 / CC;
    float a0 = 0.f, a1 = 0.f, a2 = 0.f, a3 = 0.f;

    for (int c0 = beg; c0 < end; c0 += 64) {
        int cnt = min(64, end - c0);
        if (wave < H && lane < cnt) {
            int e = c0 + lane;
            int s = col_src[e];
            float v = lrelu(asrc[s * H + wave] + ad_s[wave]);
            float wv = expf(v - m_s[wave]) * inv_s[wave];
            w_lds[lane * 4 + wave] = wv;
            if (wave == 0) src_lds[lane] = s;
            if (wout) wout[(size_t)col_eid[e] * H + wave] = wv;
        }
        __syncthreads();
        if (ch0 < HC) {
            // 2-deep prefetch pipeline
            f16x4 hva = {}, hvb = {};
            hva = *(const f16x4*)(h + (size_t)src_lds[0] * HCp + ch0);
            if (cnt > 1) hvb = *(const f16x4*)(h + (size_t)src_lds[1] * HCp + ch0);
            for (int j = 0; j < cnt; ++j) {
                f16x4 hvc = {};
                if (j + 2 < cnt) hvc = *(const f16x4*)(h + (size_t)src_lds[j + 2] * HCp + ch0);
                float wv = w_lds[j * 4 + head];
                a0 += wv * (float)hva[0];
                a1 += wv * (float)hva[1];
                a2 += wv * (float)hva[2];
                a3 += wv * (float)hva[3];
                hva = hvb; hvb = hvc;
            }
        }
        __syncthreads();
    }

    if (ch0 < HC) {
        float4 bv = *(const float4*)(bias + ch0);
        float g0 = gelu_f(a0 + bv.x), g1 = gelu_f(a1 + bv.y);
        float g2 = gelu_f(a2 + bv.z), g3 = gelu_f(a3 + bv.w);
        if (out32) {
            *(float4*)(out32 + (size_t)n * HC + ch0) = float4{g0, g1, g2, g3};
        } else {
            *(u16x4*)(apn + (size_t)n * 832 + ch0) = u16x4{
                __builtin_bit_cast(unsigned short, (_Float16)g0),
                __builtin_bit_cast(unsigned short, (_Float16)g1),
                __builtin_bit_cast(unsigned short, (_Float16)g2),
                __builtin_bit_cast(unsigned short, (_Float16)g3)};
        }
    }
}

// ---------------- host ----------------

extern "C" void kernel_launch(void* const* d_in, const int* in_sizes, int n_in,
                              void* d_out, int out_size, void* d_ws, size_t ws_size,
                              hipStream_t stream) {
    const float* X = (const float*)d_in[0];
    const int* ei = (const int*)d_in[1];

    char* ws = (char*)d_ws;
    size_t off = 0;
    auto alloc = [&](size_t bytes) { void* p = ws + off; off += (bytes + 255) & ~(size_t)255; return p; };

    unsigned short* Ap0 = (unsigned short*)alloc((size_t)MPAD * 256 * 2);       // 5.2 MB
    unsigned short* Ap  = (unsigned short*)alloc((size_t)MPAD * 832 * 2);       // 16.8 MB
    unsigned short* Bp  = (unsigned short*)alloc((size_t)5 * 896 * 832 * 2);    // 7.5 MB
    unsigned short* hbuf= (unsigned short*)alloc((size_t)MPAD * 896 * 2);       // 18.1 MB
    float* attn_all = (float*)alloc((size_t)5 * 2 * NN * 4 * 4);                // 1.6 MB
    int* src_all  = (int*)alloc((size_t)EPE * 4);
    int* dst_all  = (int*)alloc((size_t)EPE * 4);
    int* col_src  = (int*)alloc((size_t)EPE * 4);
    int* col_eid  = (int*)alloc((size_t)EPE * 4);
    int* row_ptr  = (int*)alloc((size_t)(NN + 1) * 4);
    int* degcur   = (int*)alloc((size_t)2 * NN * 4);
    int* deg = degcur, * cursor = degcur + NN;

    hipMemsetAsync(degcur, 0, 2 * NN * sizeof(int), stream);

    int eb = (EPE + 255) / 256;
    build_edges_kernel<<<eb, 256, 0, stream>>>(ei, src_all, dst_all, deg);
    scan_kernel<<<1, 1024, 0, stream>>>(deg, row_ptr, NN);
    scatter_kernel<<<eb, 256, 0, stream>>>(src_all, dst_all, row_ptr, cursor, col_src, col_eid);

    {
        int npad = NN * 32 + (MPAD - NN) * 832;
        padA_kernel<<<(npad + 255) / 256, 256, 0, stream>>>(Ap);
    }
    {
        size_t na = (size_t)MPAD * 256;
        convA_kernel<<<(int)((na + 255) / 256), 256, 0, stream>>>(X, 200, 200, 256, Ap0);
    }
    convB_all_kernel<<<dim3((896 * 832 + 255) / 256, 5), 256, 0, stream>>>(
        (const float*)d_in[2], (const float*)d_in[6], (const float*)d_in[10],
        (const float*)d_in[14], (const float*)d_in[18], Bp);

    for (int i = 0; i < 5; ++i) {
        int H   = (i == 4) ? 1 : 4;
        int HC  = H * CC;
        int Kp  = (i == 0) ? 256 : 832;
        int Np  = (i == 4) ? 256 : 896;
        int ncol = Np / 128;
        const unsigned short* Acur = (i == 0) ? Ap0 : Ap;
        const unsigned short* Bpl = Bp + (size_t)i * (896 * 832);
        const float* as_ = (const float*)d_in[3 + 4 * i];
        const float* ad_ = (const float*)d_in[4 + 4 * i];
        const float* b_  = (const float*)d_in[5 + 4 * i];
        float* asrc_l = attn_all + (size_t)i * 2 * NN * 4;
        float* adst_l = asrc_l + NN * 4;

        gemm_mfma<<<ncol * (MPAD / 128), 256, 0, stream>>>(Acur, Bpl, hbuf, Kp, Np, ncol);

        attn_kernel<<<NN, 256, 0, stream>>>(hbuf, as_, ad_, asrc_l, adst_l, H, Np);

        float* out32 = (i == 4) ? (float*)d_out : nullptr;
        unsigned short* apn = (i == 4) ? nullptr : Ap;
        float* wout = (i == 4) ? (float*)d_out + (size_t)NN * CC : nullptr;
        fused_agg_kernel<<<NN, 256, 0, stream>>>(hbuf, asrc_l, adst_l, row_ptr, col_src,
                                                 col_eid, b_, out32, apn, wout, H, HC, Np);
    }
}

// Round 12
// 441.798 us; speedup vs baseline: 1.2941x; 1.0421x over previous
//
#include <hip/hip_runtime.h>
#include <math.h>

#define NN 10000
#define EE 100000
#define EPE 110000   // edges + self loops
#define CC 200
#define MPAD 10112   // 79 * 128

typedef __attribute__((ext_vector_type(8))) _Float16 f16x8;
typedef __attribute__((ext_vector_type(4))) _Float16 f16x4;
typedef __attribute__((ext_vector_type(4))) unsigned short u16x4;
typedef __attribute__((ext_vector_type(4))) float f32x4;

__device__ __forceinline__ float lrelu(float v) { return v >= 0.f ? v : 0.2f * v; }
__device__ __forceinline__ float gelu_f(float v) { return 0.5f * v * (1.f + erff(v * 0.70710678118654752f)); }

// ---------------- CSR build ----------------

__global__ void build_edges_kernel(const int* __restrict__ ei,
                                   int* __restrict__ src_all, int* __restrict__ dst_all,
                                   int* __restrict__ deg) {
    int e = blockIdx.x * blockDim.x + threadIdx.x;
    if (e >= EPE) return;
    int s, d;
    if (e < EE) { s = ei[e]; d = ei[EE + e]; }
    else        { s = e - EE; d = e - EE; }
    src_all[e] = s;
    dst_all[e] = d;
    atomicAdd(&deg[d], 1);
}

// single-pass scan: 1 block x 1024 threads, 10 elements/thread
__global__ void scan_kernel(const int* __restrict__ deg, int* __restrict__ row_ptr) {
    int tid = threadIdx.x;
    int lane = tid & 63, w = tid >> 6;
    int base = tid * 10;
    int v[10];
    int tot = 0;
#pragma unroll
    for (int j = 0; j < 10; ++j) {
        int idx = base + j;
        v[j] = (idx < NN) ? deg[idx] : 0;
        tot += v[j];
    }
    int inc = tot;
#pragma unroll
    for (int off = 1; off < 64; off <<= 1) {
        int t = __shfl_up(inc, off);
        if (lane >= off) inc += t;
    }
    __shared__ int ws[16];
    if (lane == 63) ws[w] = inc;
    __syncthreads();
    if (w == 0) {
        int s = (lane < 16) ? ws[lane] : 0;
#pragma unroll
        for (int off = 1; off < 16; off <<= 1) {
            int t = __shfl_up(s, off);
            if (lane >= off) s += t;
        }
        if (lane < 16) ws[lane] = s;
    }
    __syncthreads();
    int excl = inc - tot + ((w > 0) ? ws[w - 1] : 0);
    int run = excl;
#pragma unroll
    for (int j = 0; j < 10; ++j) {
        int idx = base + j;
        if (idx < NN) row_ptr[idx] = run;
        run += v[j];
    }
    if (base == NN) row_ptr[NN] = excl;
}

__global__ void scatter_kernel(const int* __restrict__ src_all, const int* __restrict__ dst_all,
                               const int* __restrict__ row_ptr, int* __restrict__ cursor,
                               int* __restrict__ col_src, int* __restrict__ col_eid) {
    int e = blockIdx.x * blockDim.x + threadIdx.x;
    if (e >= EPE) return;
    int d = dst_all[e];
    int pos = row_ptr[d] + atomicAdd(&cursor[d], 1);
    col_src[pos] = src_all[e];
    col_eid[pos] = e;
}

// ---------------- mega prep kernel ----------------
// region 0: zero deg/cursor (79 blocks)
// region 1: zero Ap pad regions (1614 blocks)
// region 2: convA layer-0 fp16 (10112 blocks)
// region 3: convB transpose for all 5 layers, 32x32 LDS tiles (2616 blocks)

#define PREP_R0 79
#define PREP_R1 (PREP_R0 + 1614)
#define PREP_R2 (PREP_R1 + 10112)
#define PREP_R3 (PREP_R2 + 2616)

__global__ __launch_bounds__(256) void prep_kernel(const float* __restrict__ X,
                                                   const float* __restrict__ W0,
                                                   const float* __restrict__ W1,
                                                   const float* __restrict__ W2,
                                                   const float* __restrict__ W3,
                                                   const float* __restrict__ W4,
                                                   int* __restrict__ degcur,
                                                   unsigned short* __restrict__ Ap0,
                                                   unsigned short* __restrict__ Ap,
                                                   unsigned short* __restrict__ Bp) {
    __shared__ float tl[32][33];
    int bid = blockIdx.x;
    int tid = threadIdx.x;

    if (bid < PREP_R0) {
        int idx = bid * 256 + tid;
        if (idx < 2 * NN) degcur[idx] = 0;
        return;
    }
    if (bid < PREP_R1) {
        int idx = (bid - PREP_R0) * 256 + tid;
        if (idx < NN * 32) {
            int rw = idx >> 5, c = idx & 31;
            Ap[(size_t)rw * 832 + 800 + c] = 0;
        } else {
            int j = idx - NN * 32;
            if (j < (MPAD - NN) * 832) {
                int rw = j / 832, c = j - rw * 832;
                Ap[(size_t)(NN + rw) * 832 + c] = 0;
            }
        }
        return;
    }
    if (bid < PREP_R2) {
        int idx = (bid - PREP_R1) * 256 + tid;
        int row = idx >> 8, kk = idx & 255;
        float v = 0.f;
        if (row < NN && kk < 200) v = X[(size_t)row * 200 + kk];
        Ap0[idx] = __builtin_bit_cast(unsigned short, (_Float16)v);
        return;
    }
    // convB transpose tiles
    int t = bid - PREP_R2;
    int l, t0;
    if (t < 224)       { l = 0; t0 = 0; }
    else if (t < 952)  { l = 1; t0 = 224; }
    else if (t < 1680) { l = 2; t0 = 952; }
    else if (t < 2408) { l = 3; t0 = 1680; }
    else               { l = 4; t0 = 2408; }
    const float* W = (l == 0) ? W0 : (l == 1) ? W1 : (l == 2) ? W2 : (l == 3) ? W3 : W4;
    int Fin = (l == 0) ? 200 : 800;
    int HC  = (l == 4) ? 200 : 800;
    int Kp  = (l == 0) ? 256 : 832;
    int ntk = Kp >> 5;                 // tiles along k
    int tile = t - t0;
    int kt = tile % ntk, nt = tile / ntk;
    int n0 = nt * 32, k0 = kt * 32;
    int tx = tid & 31, ty = tid >> 5;  // 32 x 8

    // coalesced read of W (over n), staged to LDS
#pragma unroll
    for (int j = 0; j < 4; ++j) {
        int kk = k0 + ty + j * 8;
        int n  = n0 + tx;
        float v = (kk < Fin && n < HC) ? W[(size_t)kk * HC + n] : 0.f;
        tl[ty + j * 8][tx] = v;
    }
    __syncthreads();
    // coalesced write of Bp (over k)
    unsigned short* Bpl = Bp + (size_t)l * (896 * 832);
#pragma unroll
    for (int j = 0; j < 4; ++j) {
        int n  = n0 + ty + j * 8;
        int kk = k0 + tx;
        Bpl[(size_t)n * Kp + kk] =
            __builtin_bit_cast(unsigned short, (_Float16)tl[tx][ty + j * 8]);
    }
}

// ---------------- MFMA GEMM (128x128, single buffer; best measured) ----------------

__global__ __launch_bounds__(256) void gemm_mfma(const unsigned short* __restrict__ A,
                                                 const unsigned short* __restrict__ B,
                                                 unsigned short* __restrict__ C,
                                                 int Kt, int Np, int ncol) {
    __shared__ unsigned short As[8192];   // [128 rows][64 k] swizzled, 16 KB
    __shared__ unsigned short Bs[8192];

    int tid = threadIdx.x;
    int lane = tid & 63, wave = tid >> 6;

    int nwg = gridDim.x;
    int orig = blockIdx.x;
    int q = nwg >> 3, r = nwg & 7;
    int xcd = orig & 7, sidx = orig >> 3;
    int wg = (xcd < r ? xcd * (q + 1) : r * (q + 1) + (xcd - r) * q) + sidx;
    int rowT = wg / ncol, colT = wg - rowT * ncol;
    int row0 = rowT * 128, col0 = colT * 128;
    int wr = wave >> 1, wc = wave & 1;

    size_t gAoff[4], gBoff[4];
    int ldsSeg[4];
#pragma unroll
    for (int i = 0; i < 4; ++i) {
        int seg = wave * 4 + i;            // 0..15
        int chunkIdx = seg * 64 + lane;    // 0..1023
        int rr = chunkIdx >> 3;            // row 0..127
        int c = chunkIdx & 7;
        int cg = c ^ (rr & 7);             // pre-swizzled source chunk
        gAoff[i] = (size_t)(row0 + rr) * Kt + (size_t)cg * 8;
        gBoff[i] = (size_t)(col0 + rr) * Kt + (size_t)cg * 8;
        ldsSeg[i] = seg * 512;
    }

    int rowA[4], rowB[4];
#pragma unroll
    for (int m = 0; m < 4; ++m) {
        rowA[m] = wr * 64 + m * 16 + (lane & 15);
        rowB[m] = wc * 64 + m * 16 + (lane & 15);
    }

    int iaOff[2][4], ibOff[2][4];
#pragma unroll
    for (int kh = 0; kh < 2; ++kh) {
        int cw = kh * 4 + (lane >> 4);
#pragma unroll
        for (int m = 0; m < 4; ++m)
            iaOff[kh][m] = rowA[m] * 64 + ((cw ^ (rowA[m] & 7)) << 3);
#pragma unroll
        for (int n = 0; n < 4; ++n)
            ibOff[kh][n] = rowB[n] * 64 + ((cw ^ (rowB[n] & 7)) << 3);
    }

    f32x4 acc[4][4];
#pragma unroll
    for (int m = 0; m < 4; ++m)
#pragma unroll
        for (int n = 0; n < 4; ++n) acc[m][n] = f32x4{0.f, 0.f, 0.f, 0.f};

    for (int k0 = 0; k0 < Kt; k0 += 64) {
#pragma unroll
        for (int i = 0; i < 4; ++i) {
            __builtin_amdgcn_global_load_lds(
                (const __attribute__((address_space(1))) void*)(A + gAoff[i] + k0),
                (__attribute__((address_space(3))) void*)(&As[ldsSeg[i]]), 16, 0, 0);
            __builtin_amdgcn_global_load_lds(
                (const __attribute__((address_space(1))) void*)(B + gBoff[i] + k0),
                (__attribute__((address_space(3))) void*)(&Bs[ldsSeg[i]]), 16, 0, 0);
        }
        __syncthreads();

#pragma unroll
        for (int kh = 0; kh < 2; ++kh) {
            f16x8 a[4], b[4];
#pragma unroll
            for (int m = 0; m < 4; ++m) a[m] = *(const f16x8*)(&As[iaOff[kh][m]]);
#pragma unroll
            for (int n = 0; n < 4; ++n) b[n] = *(const f16x8*)(&Bs[ibOff[kh][n]]);
#pragma unroll
            for (int m = 0; m < 4; ++m)
#pragma unroll
                for (int n = 0; n < 4; ++n)
                    acc[m][n] = __builtin_amdgcn_mfma_f32_16x16x32_f16(a[m], b[n], acc[m][n], 0, 0, 0);
        }
        __syncthreads();
    }

    int crow = row0 + wr * 64 + ((lane >> 4) << 2);
    int ccol = col0 + wc * 64 + (lane & 15);
#pragma unroll
    for (int m = 0; m < 4; ++m)
#pragma unroll
        for (int j = 0; j < 4; ++j) {
            size_t rb = (size_t)(crow + m * 16 + j) * Np;
#pragma unroll
            for (int n = 0; n < 4; ++n)
                C[rb + ccol + n * 16] =
                    __builtin_bit_cast(unsigned short, (_Float16)acc[m][n][j]);
        }
}

// ---------------- attention scores (vectorized fp16 h) ----------------

__global__ void attn_kernel(const unsigned short* __restrict__ h,
                            const float* __restrict__ a_s, const float* __restrict__ a_d,
                            float* __restrict__ asrc, float* __restrict__ adst,
                            int H, int HCp) {
    int n = blockIdx.x;
    int wave = threadIdx.x >> 6;
    int lane = threadIdx.x & 63;
    float sa = 0.f, da = 0.f;
    int c0 = lane * 4;
    if (c0 < CC) {
        f16x4 hv = *(const f16x4*)(h + (size_t)n * HCp + wave * CC + c0);
        float4 av = *(const float4*)(a_s + wave * CC + c0);
        float4 dv = *(const float4*)(a_d + wave * CC + c0);
        float h0 = (float)hv[0], h1 = (float)hv[1], h2 = (float)hv[2], h3 = (float)hv[3];
        sa = h0 * av.x + h1 * av.y + h2 * av.z + h3 * av.w;
        da = h0 * dv.x + h1 * dv.y + h2 * dv.z + h3 * dv.w;
    }
#pragma unroll
    for (int off = 32; off > 0; off >>= 1) {
        sa += __shfl_down(sa, off);
        da += __shfl_down(da, off);
    }
    if (lane == 0) {
        asrc[n * H + wave] = sa;
        adst[n * H + wave] = da;
    }
}

// ---------------- fused softmax(m/den) + weights + aggregation + bias + gelu ----------------

__global__ __launch_bounds__(256) void fused_agg_kernel(const unsigned short* __restrict__ h,
                                                        const float* __restrict__ asrc,
                                                        const float* __restrict__ adst,
                                                        const int* __restrict__ row_ptr,
                                                        const int* __restrict__ col_src,
                                                        const int* __restrict__ col_eid,
                                                        const float* __restrict__ bias,
                                                        float* __restrict__ out32,
                                                        unsigned short* __restrict__ apn,
                                                        float* __restrict__ wout,
                                                        int H, int HC, int HCp) {
    int n = blockIdx.x;
    int tid = threadIdx.x;
    int wave = tid >> 6, lane = tid & 63;
    int beg = row_ptr[n], end = row_ptr[n + 1];

    __shared__ float m_s[4], inv_s[4], ad_s[4];
    __shared__ float w_lds[64 * 4];
    __shared__ int src_lds[64];

    if (wave < H) {
        float ad = adst[n * H + wave];
        float m = -1e30f, den = 0.f;
        for (int e = beg + lane; e < end; e += 64) {
            float v = lrelu(asrc[col_src[e] * H + wave] + ad);
            if (v > m) { den = den * expf(m - v) + 1.f; m = v; }
            else den += expf(v - m);
        }
#pragma unroll
        for (int off = 1; off < 64; off <<= 1) {
            float m2 = __shfl_xor(m, off);
            float d2 = __shfl_xor(den, off);
            float M = fmaxf(m, m2);
            den = den * expf(m - M) + d2 * expf(m2 - M);
            m = M;
        }
        if (lane == 0) { m_s[wave] = m; inv_s[wave] = 1.f / den; ad_s[wave] = ad; }
    }
    __syncthreads();

    int ch0 = tid * 4;
    int head = ch0 / CC;
    float a0 = 0.f, a1 = 0.f, a2 = 0.f, a3 = 0.f;

    for (int c0 = beg; c0 < end; c0 += 64) {
        int cnt = min(64, end - c0);
        if (wave < H && lane < cnt) {
            int e = c0 + lane;
            int s = col_src[e];
            float v = lrelu(asrc[s * H + wave] + ad_s[wave]);
            float wv = expf(v - m_s[wave]) * inv_s[wave];
            w_lds[lane * 4 + wave] = wv;
            if (wave == 0) src_lds[lane] = s;
            if (wout) wout[(size_t)col_eid[e] * H + wave] = wv;
        }
        __syncthreads();
        if (ch0 < HC) {
            // 2-deep prefetch pipeline
            f16x4 hva = {}, hvb = {};
            hva = *(const f16x4*)(h + (size_t)src_lds[0] * HCp + ch0);
            if (cnt > 1) hvb = *(const f16x4*)(h + (size_t)src_lds[1] * HCp + ch0);
            for (int j = 0; j < cnt; ++j) {
                f16x4 hvc = {};
                if (j + 2 < cnt) hvc = *(const f16x4*)(h + (size_t)src_lds[j + 2] * HCp + ch0);
                float wv = w_lds[j * 4 + head];
                a0 += wv * (float)hva[0];
                a1 += wv * (float)hva[1];
                a2 += wv * (float)hva[2];
                a3 += wv * (float)hva[3];
                hva = hvb; hvb = hvc;
            }
        }
        __syncthreads();
    }

    if (ch0 < HC) {
        float4 bv = *(const float4*)(bias + ch0);
        float g0 = gelu_f(a0 + bv.x), g1 = gelu_f(a1 + bv.y);
        float g2 = gelu_f(a2 + bv.z), g3 = gelu_f(a3 + bv.w);
        if (out32) {
            *(float4*)(out32 + (size_t)n * HC + ch0) = float4{g0, g1, g2, g3};
        } else {
            *(u16x4*)(apn + (size_t)n * 832 + ch0) = u16x4{
                __builtin_bit_cast(unsigned short, (_Float16)g0),
                __builtin_bit_cast(unsigned short, (_Float16)g1),
                __builtin_bit_cast(unsigned short, (_Float16)g2),
                __builtin_bit_cast(unsigned short, (_Float16)g3)};
        }
    }
}

// ---------------- host ----------------

extern "C" void kernel_launch(void* const* d_in, const int* in_sizes, int n_in,
                              void* d_out, int out_size, void* d_ws, size_t ws_size,
                              hipStream_t stream) {
    const float* X = (const float*)d_in[0];
    const int* ei = (const int*)d_in[1];

    char* ws = (char*)d_ws;
    size_t off = 0;
    auto alloc = [&](size_t bytes) { void* p = ws + off; off += (bytes + 255) & ~(size_t)255; return p; };

    unsigned short* Ap0 = (unsigned short*)alloc((size_t)MPAD * 256 * 2);       // 5.2 MB
    unsigned short* Ap  = (unsigned short*)alloc((size_t)MPAD * 832 * 2);       // 16.8 MB
    unsigned short* Bp  = (unsigned short*)alloc((size_t)5 * 896 * 832 * 2);    // 7.5 MB
    unsigned short* hbuf= (unsigned short*)alloc((size_t)MPAD * 896 * 2);       // 18.1 MB
    float* attn_all = (float*)alloc((size_t)5 * 2 * NN * 4 * 4);                // 1.6 MB
    int* src_all  = (int*)alloc((size_t)EPE * 4);
    int* dst_all  = (int*)alloc((size_t)EPE * 4);
    int* col_src  = (int*)alloc((size_t)EPE * 4);
    int* col_eid  = (int*)alloc((size_t)EPE * 4);
    int* row_ptr  = (int*)alloc((size_t)(NN + 1) * 4);
    int* degcur   = (int*)alloc((size_t)2 * NN * 4);
    int* deg = degcur, * cursor = degcur + NN;

    // one mega prep dispatch: zero deg/cursor, Ap pads, convA(layer0), convB(all, transposed)
    prep_kernel<<<PREP_R3, 256, 0, stream>>>(X,
        (const float*)d_in[2], (const float*)d_in[6], (const float*)d_in[10],
        (const float*)d_in[14], (const float*)d_in[18],
        degcur, Ap0, Ap, Bp);

    int eb = (EPE + 255) / 256;
    build_edges_kernel<<<eb, 256, 0, stream>>>(ei, src_all, dst_all, deg);
    scan_kernel<<<1, 1024, 0, stream>>>(deg, row_ptr);
    scatter_kernel<<<eb, 256, 0, stream>>>(src_all, dst_all, row_ptr, cursor, col_src, col_eid);

    for (int i = 0; i < 5; ++i) {
        int H   = (i == 4) ? 1 : 4;
        int HC  = H * CC;
        int Kp  = (i == 0) ? 256 : 832;
        int Np  = (i == 4) ? 256 : 896;
        int ncol = Np / 128;
        const unsigned short* Acur = (i == 0) ? Ap0 : Ap;
        const unsigned short* Bpl = Bp + (size_t)i * (896 * 832);
        const float* as_ = (const float*)d_in[3 + 4 * i];
        const float* ad_ = (const float*)d_in[4 + 4 * i];
        const float* b_  = (const float*)d_in[5 + 4 * i];
        float* asrc_l = attn_all + (size_t)i * 2 * NN * 4;
        float* adst_l = asrc_l + NN * 4;

        gemm_mfma<<<ncol * (MPAD / 128), 256, 0, stream>>>(Acur, Bpl, hbuf, Kp, Np, ncol);

        attn_kernel<<<NN, H * 64, 0, stream>>>(hbuf, as_, ad_, asrc_l, adst_l, H, Np);

        float* out32 = (i == 4) ? (float*)d_out : nullptr;
        unsigned short* apn = (i == 4) ? nullptr : Ap;
        float* wout = (i == 4) ? (float*)d_out + (size_t)NN * CC : nullptr;
        fused_agg_kernel<<<NN, 256, 0, stream>>>(hbuf, asrc_l, adst_l, row_ptr, col_src,
                                                 col_eid, b_, out32, apn, wout, H, HC, Np);
    }
}